// Round 23
// baseline (668.202 us; speedup 1.0000x reference)
//
#include <hip/hip_runtime.h>
#include <hip/hip_bf16.h>

// ---------------------------------------------------------------------------
// RecurrentBattleNet: 2-layer LSTM (B=512, T=256, IN=512, H=128) + FC head.
// Round 23: isolation recombination. R21/R22 showed the dual-accumulator
// split is the toxic half of R21's bundle (R22's producer-load fix changed
// nothing -> producer path exonerated). This round: R20's single-acc K=256
// consumer + R21's bf16 xp stream (ushort loads, halved GEMM writes &
// producer FETCH). Everything else = R20 skeleton.
// ---------------------------------------------------------------------------

#define BATCH 512
#define SEQT  256
#define INPUTD 512
#define HID   128
#define GATES 512   // 4*HID
#define RB    4     // batch rows per recurrence block
#define SUBS  16    // producer->consumer flag granularity (steps)
#define NCH   (SEQT / SUBS)

typedef __bf16 bf16_t;
typedef bf16_t bf16x4 __attribute__((ext_vector_type(4)));
typedef bf16_t bf16x8 __attribute__((ext_vector_type(8)));
typedef float  f32x4  __attribute__((ext_vector_type(4)));

__device__ __forceinline__ float sigm(float x) {
    return __builtin_amdgcn_rcpf(1.f + __expf(-x));
}
__device__ __forceinline__ float tanhfast(float x) {
    float xc = fminf(fmaxf(x, -15.f), 15.f);
    float e = __expf(2.f * xc);
    return (e - 1.f) * __builtin_amdgcn_rcpf(e + 1.f);
}
// bf16 (as ushort) -> f32 without d16 partial-register loads
__device__ __forceinline__ float bf16f(unsigned u) {
    return __builtin_bit_cast(float, u << 16);
}

// ---------------------------------------------------------------------------
// Weights f32->bf16 (4 matrices) in one launch; block 448 zeroes the flags.
// ---------------------------------------------------------------------------
__global__ __launch_bounds__(256) void cvt_weights(
    const float* __restrict__ w0, const float* __restrict__ w1,
    const float* __restrict__ w2, const float* __restrict__ w3,
    bf16_t* __restrict__ o0, bf16_t* __restrict__ o1,
    bf16_t* __restrict__ o2, bf16_t* __restrict__ o3,
    unsigned* __restrict__ flags)
{
    int b = blockIdx.x;
    if (b == 448) {
        uint4 z = make_uint4(0u, 0u, 0u, 0u);
        #pragma unroll
        for (int i = 0; i < 4; ++i)
            ((uint4*)flags)[i * 256 + threadIdx.x] = z;
        return;
    }
    const float* src; bf16_t* dst; long base;
    if (b < 256)      { src = w0; dst = o0; base = (long)b * 256; }
    else if (b < 320) { src = w1; dst = o1; base = (long)(b - 256) * 256; }
    else if (b < 384) { src = w2; dst = o2; base = (long)(b - 320) * 256; }
    else              { src = w3; dst = o3; base = (long)(b - 384) * 256; }
    long i = base + threadIdx.x;
    float4 v = ((const float4*)src)[i];
    bf16x4 r;
    r[0] = (bf16_t)v.x; r[1] = (bf16_t)v.y;
    r[2] = (bf16_t)v.z; r[3] = (bf16_t)v.w;
    ((bf16x4*)dst)[i] = r;
}

// ---------------------------------------------------------------------------
// bf16 MFMA GEMM (layer-0 input projection), A read as f32 with in-register
// cvt. Writes gate-major BF16 xp: xp4[b>>2][t][gate][(b&3)*128 + hid]
// ---------------------------------------------------------------------------
__global__ __launch_bounds__(256) void gemm_mfma(
    const float* __restrict__ A, const bf16_t* __restrict__ W,
    const float* __restrict__ b1, const float* __restrict__ b2,
    bf16_t* __restrict__ out,
    int K, int tcs, int tcmask, int srcT, int t0)
{
    __shared__ bf16_t As[128 * 32];
    __shared__ bf16_t Bs[128 * 32];
    int tid = threadIdx.x;
    int l = tid & 63;
    int w = tid >> 6;
    int wm = w >> 1, wn = w & 1;
    int bn = blockIdx.x;
    int bm = blockIdx.y;
    int Tc = tcmask + 1;

    long aoff[2], boff[2];
    #pragma unroll
    for (int c = 0; c < 2; ++c) {
        int m = bm * 128 + (tid >> 2) + 64 * c;
        int xr = ((m >> tcs) * srcT) + t0 + (m & tcmask);
        aoff[c] = (long)xr * K + (tid & 3) * 8;
        int n = bn * 128 + (tid >> 2) + 64 * c;
        boff[c] = (long)n * K + (tid & 3) * 8;
    }

    f32x4 acc[4][4];
    #pragma unroll
    for (int i = 0; i < 4; ++i)
        #pragma unroll
        for (int j = 0; j < 4; ++j)
            acc[i][j] = (f32x4){0.f, 0.f, 0.f, 0.f};

    const int rbase = wm * 64 + (l & 15);
    const int cbase = wn * 64 + (l & 15);
    const int kfrag = (l >> 4) * 8;

    for (int kt = 0; kt < K; kt += 32) {
        float4 av[2][2];
        #pragma unroll
        for (int c = 0; c < 2; ++c) {
            av[c][0] = *(const float4*)(A + aoff[c] + kt);
            av[c][1] = *(const float4*)(A + aoff[c] + kt + 4);
        }
        __builtin_amdgcn_global_load_lds(
            (const __attribute__((address_space(1))) void*)(W + boff[0] + kt),
            (__attribute__((address_space(3))) void*)(Bs + tid * 8), 16, 0, 0);
        __builtin_amdgcn_global_load_lds(
            (const __attribute__((address_space(1))) void*)(W + boff[1] + kt),
            (__attribute__((address_space(3))) void*)(Bs + 2048 + tid * 8), 16, 0, 0);
        #pragma unroll
        for (int c = 0; c < 2; ++c) {
            bf16x8 ab;
            ab[0] = (bf16_t)av[c][0].x; ab[1] = (bf16_t)av[c][0].y;
            ab[2] = (bf16_t)av[c][0].z; ab[3] = (bf16_t)av[c][0].w;
            ab[4] = (bf16_t)av[c][1].x; ab[5] = (bf16_t)av[c][1].y;
            ab[6] = (bf16_t)av[c][1].z; ab[7] = (bf16_t)av[c][1].w;
            *(bf16x8*)(As + c * 2048 + tid * 8) = ab;
        }
        __syncthreads();

        bf16x8 af[4], bfr[4];
        #pragma unroll
        for (int i = 0; i < 4; ++i)
            af[i] = *(const bf16x8*)(As + (rbase + i * 16) * 32 + kfrag);
        #pragma unroll
        for (int j = 0; j < 4; ++j)
            bfr[j] = *(const bf16x8*)(Bs + (cbase + j * 16) * 32 + kfrag);

        #pragma unroll
        for (int i = 0; i < 4; ++i)
            #pragma unroll
            for (int j = 0; j < 4; ++j)
                acc[i][j] = __builtin_amdgcn_mfma_f32_16x16x32_bf16(
                    af[i], bfr[j], acc[i][j], 0, 0, 0);
        __syncthreads();
    }

    #pragma unroll
    for (int i = 0; i < 4; ++i) {
        int m0 = bm * 128 + wm * 64 + i * 16 + (l >> 4) * 4;
        #pragma unroll
        for (int j = 0; j < 4; ++j) {
            int n = bn * 128 + wn * 64 + j * 16 + (l & 15);
            float bb = b1[n] + b2[n];
            int hid = n & 127;          // g == bn
            #pragma unroll
            for (int r = 0; r < 4; ++r) {
                int m = m0 + r;
                int b = m >> tcs;
                int t = m & tcmask;
                int br = b >> 2, brow = b & 3;
                out[(((long)br * Tc + t) * 4 + bn) * 512 + brow * 128 + hid] =
                    (bf16_t)(acc[i][j][r] + bb);
            }
        }
    }
}

// ---------------------------------------------------------------------------
// Dual-role recurrence kernel. 256 blocks x 512 threads.
//   blocks 0-127  : layer-0 recurrence (producer)
//   blocks 128-255: layer-1 recurrence (consumer, K=256 stacked SINGLE acc,
//                   depth-2 DMA)
// ---------------------------------------------------------------------------
#define BARRIER_()                                                             \
    do {                                                                       \
        asm volatile("s_waitcnt lgkmcnt(0)" ::: "memory");                     \
        __builtin_amdgcn_s_barrier();                                          \
        __builtin_amdgcn_sched_barrier(0);                                     \
    } while (0)

#define REC0_STEP(X, t)                                                        \
    {                                                                          \
        bf16x8 a[4];                                                           \
        _Pragma("unroll")                                                      \
        for (int ks = 0; ks < 4; ++ks) {                                       \
            int ba = (col * 256 + ks * 64 + lgroup * 16) ^ ((col & 7) << 4);   \
            a[ks] = *(const bf16x8*)((const char*)h_lds + ba);                 \
        }                                                                      \
        f32x4 acc[4];                                                          \
        _Pragma("unroll")                                                      \
        for (int g = 0; g < 4; ++g) acc[g] = (f32x4){0.f, 0.f, 0.f, 0.f};      \
        _Pragma("unroll")                                                      \
        for (int ks = 0; ks < 4; ++ks)                                         \
            _Pragma("unroll")                                                  \
            for (int g = 0; g < 4; ++g)                                        \
                acc[g] = __builtin_amdgcn_mfma_f32_16x16x32_bf16(              \
                    a[ks], __builtin_bit_cast(bf16x8, wreg[g][ks]), acc[g],    \
                    0, 0, 0);                                                  \
        if (lgroup == 0) {                                                     \
            _Pragma("unroll")                                                  \
            for (int r = 0; r < 4; ++r) {                                      \
                f32x4 v;                                                       \
                v[0] = acc[0][r]; v[1] = acc[1][r];                            \
                v[2] = acc[2][r]; v[3] = acc[3][r];                            \
                *(f32x4*)((char*)g_lds + r * 2048 + coff * 16) = v;            \
            }                                                                  \
        }                                                                      \
        BARRIER_();                                                            \
        {                                                                      \
            f32x4 gv = *(const f32x4*)((const char*)g_lds + tid * 16);         \
            float zi = gv[0] + X.x, zf = gv[1] + X.y;                          \
            float zg = gv[2] + X.z, zo = gv[3] + X.w;                          \
            c = sigm(zf) * c + sigm(zi) * tanhfast(zg);                        \
            h = sigm(zo) * tanhfast(c);                                        \
            *(bf16_t*)((char*)h_lds + hba) = (bf16_t)h;                        \
            h0qp[(long)(t) * 512] = (bf16_t)h;                                 \
        }                                                                      \
        if ((t) + 2 < Tc) {                                                    \
            long o = (long)((t) + 2) * 2048;                                   \
            unsigned u0 = xpu[o], u1 = xpu[o + 512];                           \
            unsigned u2 = xpu[o + 1024], u3 = xpu[o + 1536];                   \
            X.x = bf16f(u0); X.y = bf16f(u1);                                  \
            X.z = bf16f(u2); X.w = bf16f(u3);                                  \
        }                                                                      \
        if (((t) & (SUBS - 1)) == SUBS - 1)                                    \
            asm volatile("s_waitcnt vmcnt(0)" ::: "memory");                   \
        BARRIER_();                                                            \
        if ((((t) & (SUBS - 1)) == SUBS - 1) && tid == 0) {                    \
            __threadfence();                                                   \
            __hip_atomic_store(flagp + ((t) >> 4), 1u, __ATOMIC_RELEASE,       \
                               __HIP_MEMORY_SCOPE_AGENT);                      \
        }                                                                      \
    }

__global__ __launch_bounds__(512, 2) void lstm_dual(
    const bf16_t* __restrict__ xp4,  // [B/4][Tc][4][512] layer-0 proj (bf16)
    const bf16_t* __restrict__ Wh0,  // Whh0 bf16 [512][128]
    const bf16_t* __restrict__ Wi1,  // Wih1 bf16 [512][128]
    const bf16_t* __restrict__ Wh1,  // Whh1 bf16 [512][128]
    const float* __restrict__ bih1, const float* __restrict__ bhh1,
    bf16_t* __restrict__ h0q,        // [128][Tc][512] swizzled h0 images
    unsigned* __restrict__ flags,    // [128][NCH]
    float* __restrict__ h0st, float* __restrict__ c0st,
    float* __restrict__ h1st, float* __restrict__ c1st,
    int Tc, int first, int subbase)
{
    __shared__ __align__(16) char pool[28 * 1024];
    int tid = threadIdx.x;
    int l = tid & 63;
    int wv = tid >> 6;                // wave 0..7
    int pair = blockIdx.x & 127;
    int r0 = pair * RB;
    int col = l & 15;
    int lgroup = l >> 4;              // 0..3
    int kreg = lgroup * 8;
    int coff = wv * 16 + col;         // owned gate-col (0..127)
    int erow = tid >> 7, ehid = tid & 127;
    const int hba = (erow * 256 + ehid * 2) ^ ((erow & 7) << 4);
    unsigned* flagp = flags + pair * NCH + subbase;

    if (blockIdx.x < 128) {
        // ================= producer: layer-0 recurrence =================
        bf16_t* h_lds = (bf16_t*)pool;           // 4 KB (16 rows, swizzled)
        float*  g_lds = (float*)(pool + 4096);   // 8 KB

        f32x4 wreg[4][4];
        #pragma unroll
        for (int g = 0; g < 4; ++g)
            #pragma unroll
            for (int ks = 0; ks < 4; ++ks)
                wreg[g][ks] = *(const f32x4*)(Wh0 + (long)(g * 128 + coff) * HID
                                              + ks * 32 + kreg);
        #pragma unroll
        for (int g = 0; g < 4; ++g)
            #pragma unroll
            for (int ks = 0; ks < 4; ++ks)
                asm volatile("" : "+a"(wreg[g][ks]));

        float c = first ? 0.f : c0st[(r0 + erow) * HID + ehid];
        float h = first ? 0.f : h0st[(r0 + erow) * HID + ehid];

        ((float2*)h_lds)[tid & 255] = make_float2(0.f, 0.f);   // zero 4 KB
        __syncthreads();
        *(bf16_t*)((char*)h_lds + hba) = (bf16_t)h;
        __syncthreads();

        const unsigned short* xpu =
            (const unsigned short*)(xp4 + (long)pair * Tc * 2048) + tid;
        bf16_t* h0qp = h0q + (long)pair * Tc * 512 + (hba >> 1);
        float4 xA, xB;
        {
            unsigned u0 = xpu[0], u1 = xpu[512], u2 = xpu[1024], u3 = xpu[1536];
            xA.x = bf16f(u0); xA.y = bf16f(u1);
            xA.z = bf16f(u2); xA.w = bf16f(u3);
        }
        if (Tc > 1) {
            unsigned u0 = xpu[2048], u1 = xpu[2048 + 512];
            unsigned u2 = xpu[2048 + 1024], u3 = xpu[2048 + 1536];
            xB.x = bf16f(u0); xB.y = bf16f(u1);
            xB.z = bf16f(u2); xB.w = bf16f(u3);
        } else {
            xB = make_float4(0.f, 0.f, 0.f, 0.f);
        }

        for (int tt = 0; tt < Tc; tt += 2) {
            REC0_STEP(xA, tt)
            REC0_STEP(xB, tt + 1)
        }

        h0st[(r0 + erow) * HID + ehid] = h;
        c0st[(r0 + erow) * HID + ehid] = c;
    } else {
        // == consumer: layer-1, K=256 stacked (single acc), depth-2 DMA ==
        bf16_t* h0stg = (bf16_t*)pool;             // 4 slots x 4 KB
        bf16_t* h1_lds = (bf16_t*)(pool + 16384);  // 4 KB
        float*  g_lds = (float*)(pool + 20480);    // 8 KB (full gates)

        f32x4 wI[4][4], wH[4][4];
        #pragma unroll
        for (int g = 0; g < 4; ++g)
            #pragma unroll
            for (int ks = 0; ks < 4; ++ks) {
                long o = (long)(g * 128 + coff) * HID + ks * 32 + kreg;
                wI[g][ks] = *(const f32x4*)(Wi1 + o);
                wH[g][ks] = *(const f32x4*)(Wh1 + o);
            }
        #pragma unroll
        for (int g = 0; g < 4; ++g)
            #pragma unroll
            for (int ks = 0; ks < 4; ++ks) {
                asm volatile("" : "+a"(wI[g][ks]));
                asm volatile("" : "+a"(wH[g][ks]));
            }

        float4 bias1;
        bias1.x = bih1[ehid]       + bhh1[ehid];
        bias1.y = bih1[128 + ehid] + bhh1[128 + ehid];
        bias1.z = bih1[256 + ehid] + bhh1[256 + ehid];
        bias1.w = bih1[384 + ehid] + bhh1[384 + ehid];

        float c1 = first ? 0.f : c1st[(r0 + erow) * HID + ehid];
        float h1 = first ? 0.f : h1st[(r0 + erow) * HID + ehid];

        // zero h0stg (16 KB) + h1_lds (4 KB)
        #pragma unroll
        for (int i = 0; i < 5; ++i)
            ((float2*)pool)[i * 512 + tid] = make_float2(0.f, 0.f);
        __syncthreads();
        *(bf16_t*)((char*)h1_lds + hba) = (bf16_t)h1;
        __syncthreads();

        // prologue: wait chunk 0; stage images 0 and 1 into slots 0,1
        if (wv == 0) {
            while (__hip_atomic_load(flagp, __ATOMIC_ACQUIRE,
                                     __HIP_MEMORY_SCOPE_AGENT) == 0u)
                __builtin_amdgcn_s_sleep(2);
            __builtin_amdgcn_global_load_lds(
                (const __attribute__((address_space(1))) void*)(
                    h0q + (long)pair * Tc * 512 + l * 8),
                (__attribute__((address_space(3))) void*)h0stg, 16, 0, 0);
            if (Tc > 1)
                __builtin_amdgcn_global_load_lds(
                    (const __attribute__((address_space(1))) void*)(
                        h0q + ((long)pair * Tc + 1) * 512 + l * 8),
                    (__attribute__((address_space(3))) void*)(h0stg + 2048),
                    16, 0, 0);
            asm volatile("s_waitcnt vmcnt(0)" ::: "memory");
        }
        __syncthreads();

        for (int t = 0; t < Tc; ++t) {
            // issue DMA for image t+2 into slot (t+2)&3 (wave t&3)
            if (t + 2 < Tc && wv == (t & 3)) {
                if (((t + 2) & (SUBS - 1)) == 0) {
                    unsigned* fp = flagp + ((t + 2) >> 4);
                    while (__hip_atomic_load(fp, __ATOMIC_ACQUIRE,
                                             __HIP_MEMORY_SCOPE_AGENT) == 0u)
                        __builtin_amdgcn_s_sleep(2);
                }
                __builtin_amdgcn_global_load_lds(
                    (const __attribute__((address_space(1))) void*)(
                        h0q + ((long)pair * Tc + t + 2) * 512 + l * 8),
                    (__attribute__((address_space(3))) void*)(
                        h0stg + ((t + 2) & 3) * 2048), 16, 0, 0);
            }

            // phase A: full gates = Wi1@h0[t] + Wh1@h1[t-1] (K=256, 1 acc)
            const char* sb = (const char*)h0stg + (t & 3) * 4096;
            bf16x8 a0[4], a1[4];
            #pragma unroll
            for (int ks = 0; ks < 4; ++ks) {
                int ba = (col * 256 + ks * 64 + lgroup * 16) ^ ((col & 7) << 4);
                a0[ks] = *(const bf16x8*)(sb + ba);
                a1[ks] = *(const bf16x8*)((const char*)h1_lds + ba);
            }
            f32x4 acc[4];
            #pragma unroll
            for (int g = 0; g < 4; ++g) acc[g] = (f32x4){0.f, 0.f, 0.f, 0.f};
            #pragma unroll
            for (int ks = 0; ks < 4; ++ks)
                #pragma unroll
                for (int g = 0; g < 4; ++g)
                    acc[g] = __builtin_amdgcn_mfma_f32_16x16x32_bf16(
                        a0[ks], __builtin_bit_cast(bf16x8, wI[g][ks]), acc[g],
                        0, 0, 0);
            #pragma unroll
            for (int ks = 0; ks < 4; ++ks)
                #pragma unroll
                for (int g = 0; g < 4; ++g)
                    acc[g] = __builtin_amdgcn_mfma_f32_16x16x32_bf16(
                        a1[ks], __builtin_bit_cast(bf16x8, wH[g][ks]), acc[g],
                        0, 0, 0);
            if (lgroup == 0) {
                #pragma unroll
                for (int r = 0; r < 4; ++r) {
                    f32x4 v;
                    v[0] = acc[0][r]; v[1] = acc[1][r];
                    v[2] = acc[2][r]; v[3] = acc[3][r];
                    *(f32x4*)((char*)g_lds + r * 2048 + coff * 16) = v;
                }
            }
            BARRIER_();

            // phase B: ew (1 read + bias, 1 unit/thread)
            {
                f32x4 gv = *(const f32x4*)((const char*)g_lds + tid * 16);
                float zi = gv[0] + bias1.x;
                float zf = gv[1] + bias1.y;
                float zg = gv[2] + bias1.z;
                float zo = gv[3] + bias1.w;
                c1 = sigm(zf) * c1 + sigm(zi) * tanhfast(zg);
                h1 = sigm(zo) * tanhfast(c1);
                *(bf16_t*)((char*)h1_lds + hba) = (bf16_t)h1;
            }
            // wave ((t+3)&3) issued DMA(t+1) at step t-1: wait now
            if (t + 1 < Tc && wv == ((t + 3) & 3))
                asm volatile("s_waitcnt vmcnt(0)" ::: "memory");
            BARRIER_();
        }

        h1st[(r0 + erow) * HID + ehid] = h1;
        c1st[(r0 + erow) * HID + ehid] = c1;
    }
}

// ---------------------------------------------------------------------------
// FC head + softmax + state copy-out. One block per batch row, 128 threads.
// out layout: probs [512*10] | h_n [2*512*128] | c_n [2*512*128]
// ---------------------------------------------------------------------------
__global__ __launch_bounds__(128) void fc_head(
    const float* __restrict__ h0st, const float* __restrict__ c0st,
    const float* __restrict__ h1st, const float* __restrict__ c1st,
    const float* __restrict__ fc1w, const float* __restrict__ fc1b,
    const float* __restrict__ fc2w, const float* __restrict__ fc2b,
    float* __restrict__ out)
{
    __shared__ float h1_s[HID];
    __shared__ float hid_s[64];
    __shared__ float log_s[10];
    int t = threadIdx.x;
    int b = blockIdx.x;

    h1_s[t] = h1st[b * HID + t];
    __syncthreads();

    if (t < 64) {
        float a = fc1b[t];
        const float* wrow = fc1w + t * HID;
        #pragma unroll 4
        for (int k = 0; k < HID; ++k) a = fmaf(wrow[k], h1_s[k], a);
        hid_s[t] = fmaxf(a, 0.f);
    }
    __syncthreads();

    if (t < 10) {
        float a = fc2b[t];
        const float* wrow = fc2w + t * 64;
        #pragma unroll 4
        for (int k = 0; k < 64; ++k) a = fmaf(wrow[k], hid_s[k], a);
        log_s[t] = a;
    }
    __syncthreads();

    if (t == 0) {
        float m = log_s[0];
        #pragma unroll
        for (int j = 1; j < 10; ++j) m = fmaxf(m, log_s[j]);
        float e[10];
        float s = 0.f;
        #pragma unroll
        for (int j = 0; j < 10; ++j) { e[j] = __expf(log_s[j] - m); s += e[j]; }
        float inv = __builtin_amdgcn_rcpf(s);
        #pragma unroll
        for (int j = 0; j < 10; ++j) out[b * 10 + j] = e[j] * inv;
    }

    float* hn = out + BATCH * 10;
    float* cn = hn + 2 * BATCH * HID;
    hn[b * HID + t] = h0st[b * HID + t];
    hn[BATCH * HID + b * HID + t] = h1_s[t];
    cn[b * HID + t] = c0st[b * HID + t];
    cn[BATCH * HID + b * HID + t] = c1st[b * HID + t];
}

// ---------------------------------------------------------------------------
extern "C" void kernel_launch(void* const* d_in, const int* in_sizes, int n_in,
                              void* d_out, int out_size, void* d_ws, size_t ws_size,
                              hipStream_t stream) {
    const float* x    = (const float*)d_in[0];
    const float* Wih0 = (const float*)d_in[1];
    const float* Whh0 = (const float*)d_in[2];
    const float* bih0 = (const float*)d_in[3];
    const float* bhh0 = (const float*)d_in[4];
    const float* Wih1 = (const float*)d_in[5];
    const float* Whh1 = (const float*)d_in[6];
    const float* bih1 = (const float*)d_in[7];
    const float* bhh1 = (const float*)d_in[8];
    const float* fc1w = (const float*)d_in[9];
    const float* fc1b = (const float*)d_in[10];
    const float* fc2w = (const float*)d_in[11];
    const float* fc2b = (const float*)d_in[12];
    float* out = (float*)d_out;

    int Tc = SEQT;
    while (Tc > SUBS) {
        size_t need = (size_t)BATCH * Tc * GATES * 2        // xp4 (bf16)
                    + ((size_t)GATES * INPUTD + 3 * (size_t)GATES * HID) * 2
                    + (size_t)128 * Tc * 512 * 2            // h0q
                    + 4 * (size_t)BATCH * HID * 4
                    + 128 * NCH * 4 + 512;
        if (need <= ws_size) break;
        Tc >>= 1;
    }
    int tcs = __builtin_ctz((unsigned)Tc);

    bf16_t*   xp   = (bf16_t*)d_ws;
    bf16_t*   wb0  = xp + (size_t)BATCH * Tc * GATES;
    bf16_t*   wb1  = wb0 + (size_t)GATES * INPUTD;
    bf16_t*   wh0b = wb1 + (size_t)GATES * HID;
    bf16_t*   wh1b = wh0b + (size_t)GATES * HID;
    bf16_t*   h0q  = wh1b + (size_t)GATES * HID;
    float*    h0st = (float*)(h0q + (size_t)128 * Tc * 512);
    float*    c0st = h0st + (size_t)BATCH * HID;
    float*    h1st = c0st + (size_t)BATCH * HID;
    float*    c1st = h1st + (size_t)BATCH * HID;
    unsigned* flags = (unsigned*)(c1st + (size_t)BATCH * HID);

    cvt_weights<<<449, 256, 0, stream>>>(Wih0, Wih1, Whh0, Whh1,
                                         wb0, wb1, wh0b, wh1b, flags);

    int nchunk = SEQT / Tc;
    dim3 gemm_grid(GATES / 128, (BATCH * Tc) / 128);

    for (int ci = 0; ci < nchunk; ++ci) {
        gemm_mfma<<<gemm_grid, 256, 0, stream>>>(
            x, wb0, bih0, bhh0, xp, INPUTD, tcs, Tc - 1, SEQT, ci * Tc);
        lstm_dual<<<256, 512, 0, stream>>>(
            xp, wh0b, wb1, wh1b, bih1, bhh1, h0q, flags,
            h0st, c0st, h1st, c1st, Tc, ci == 0, ci * (Tc / SUBS));
    }

    fc_head<<<BATCH, 128, 0, stream>>>(
        h0st, c0st, h1st, c1st, fc1w, fc1b, fc2w, fc2b, out);
}

// Round 24
// 567.782 us; speedup vs baseline: 1.1769x; 1.1769x over previous
//
#include <hip/hip_runtime.h>
#include <hip/hip_bf16.h>

// ---------------------------------------------------------------------------
// RecurrentBattleNet: 2-layer LSTM (B=512, T=256, IN=512, H=128) + FC head.
// Round 24: REVERT to R20 verbatim — the empirically best configuration
// (569.5us). R21-R23 completed the ablation: bf16-xp (2-byte loads lose
// dword coalescing on the latency-critical producer path; 32B GEMM store
// runs) regresses ~+90us regardless of consumer acc structure. R20 =
// fp32 xp + single-acc K=256 consumer + depth-2 DMA + 2-barrier g_lds ew.
// ---------------------------------------------------------------------------

#define BATCH 512
#define SEQT  256
#define INPUTD 512
#define HID   128
#define GATES 512   // 4*HID
#define RB    4     // batch rows per recurrence block
#define SUBS  16    // producer->consumer flag granularity (steps)
#define NCH   (SEQT / SUBS)

typedef __bf16 bf16_t;
typedef bf16_t bf16x4 __attribute__((ext_vector_type(4)));
typedef bf16_t bf16x8 __attribute__((ext_vector_type(8)));
typedef float  f32x4  __attribute__((ext_vector_type(4)));

__device__ __forceinline__ float sigm(float x) {
    return __builtin_amdgcn_rcpf(1.f + __expf(-x));
}
__device__ __forceinline__ float tanhfast(float x) {
    float xc = fminf(fmaxf(x, -15.f), 15.f);
    float e = __expf(2.f * xc);
    return (e - 1.f) * __builtin_amdgcn_rcpf(e + 1.f);
}

// ---------------------------------------------------------------------------
// Weights f32->bf16 (4 matrices) in one launch; block 448 zeroes the flags.
// ---------------------------------------------------------------------------
__global__ __launch_bounds__(256) void cvt_weights(
    const float* __restrict__ w0, const float* __restrict__ w1,
    const float* __restrict__ w2, const float* __restrict__ w3,
    bf16_t* __restrict__ o0, bf16_t* __restrict__ o1,
    bf16_t* __restrict__ o2, bf16_t* __restrict__ o3,
    unsigned* __restrict__ flags)
{
    int b = blockIdx.x;
    if (b == 448) {
        uint4 z = make_uint4(0u, 0u, 0u, 0u);
        #pragma unroll
        for (int i = 0; i < 4; ++i)
            ((uint4*)flags)[i * 256 + threadIdx.x] = z;
        return;
    }
    const float* src; bf16_t* dst; long base;
    if (b < 256)      { src = w0; dst = o0; base = (long)b * 256; }
    else if (b < 320) { src = w1; dst = o1; base = (long)(b - 256) * 256; }
    else if (b < 384) { src = w2; dst = o2; base = (long)(b - 320) * 256; }
    else              { src = w3; dst = o3; base = (long)(b - 384) * 256; }
    long i = base + threadIdx.x;
    float4 v = ((const float4*)src)[i];
    bf16x4 r;
    r[0] = (bf16_t)v.x; r[1] = (bf16_t)v.y;
    r[2] = (bf16_t)v.z; r[3] = (bf16_t)v.w;
    ((bf16x4*)dst)[i] = r;
}

// ---------------------------------------------------------------------------
// bf16 MFMA GEMM (layer-0 input projection), A read as f32 with in-register
// cvt (fused x conversion). Writes gate-major fp32 xp:
//   xp4[b>>2][t][gate][(b&3)*128 + hid]   (float)
// ---------------------------------------------------------------------------
__global__ __launch_bounds__(256) void gemm_mfma(
    const float* __restrict__ A, const bf16_t* __restrict__ W,
    const float* __restrict__ b1, const float* __restrict__ b2,
    float* __restrict__ out,
    int K, int tcs, int tcmask, int srcT, int t0)
{
    __shared__ bf16_t As[128 * 32];
    __shared__ bf16_t Bs[128 * 32];
    int tid = threadIdx.x;
    int l = tid & 63;
    int w = tid >> 6;
    int wm = w >> 1, wn = w & 1;
    int bn = blockIdx.x;
    int bm = blockIdx.y;
    int Tc = tcmask + 1;

    long aoff[2], boff[2];
    #pragma unroll
    for (int c = 0; c < 2; ++c) {
        int m = bm * 128 + (tid >> 2) + 64 * c;
        int xr = ((m >> tcs) * srcT) + t0 + (m & tcmask);
        aoff[c] = (long)xr * K + (tid & 3) * 8;
        int n = bn * 128 + (tid >> 2) + 64 * c;
        boff[c] = (long)n * K + (tid & 3) * 8;
    }

    f32x4 acc[4][4];
    #pragma unroll
    for (int i = 0; i < 4; ++i)
        #pragma unroll
        for (int j = 0; j < 4; ++j)
            acc[i][j] = (f32x4){0.f, 0.f, 0.f, 0.f};

    const int rbase = wm * 64 + (l & 15);
    const int cbase = wn * 64 + (l & 15);
    const int kfrag = (l >> 4) * 8;

    for (int kt = 0; kt < K; kt += 32) {
        float4 av[2][2];
        #pragma unroll
        for (int c = 0; c < 2; ++c) {
            av[c][0] = *(const float4*)(A + aoff[c] + kt);
            av[c][1] = *(const float4*)(A + aoff[c] + kt + 4);
        }
        __builtin_amdgcn_global_load_lds(
            (const __attribute__((address_space(1))) void*)(W + boff[0] + kt),
            (__attribute__((address_space(3))) void*)(Bs + tid * 8), 16, 0, 0);
        __builtin_amdgcn_global_load_lds(
            (const __attribute__((address_space(1))) void*)(W + boff[1] + kt),
            (__attribute__((address_space(3))) void*)(Bs + 2048 + tid * 8), 16, 0, 0);
        #pragma unroll
        for (int c = 0; c < 2; ++c) {
            bf16x8 ab;
            ab[0] = (bf16_t)av[c][0].x; ab[1] = (bf16_t)av[c][0].y;
            ab[2] = (bf16_t)av[c][0].z; ab[3] = (bf16_t)av[c][0].w;
            ab[4] = (bf16_t)av[c][1].x; ab[5] = (bf16_t)av[c][1].y;
            ab[6] = (bf16_t)av[c][1].z; ab[7] = (bf16_t)av[c][1].w;
            *(bf16x8*)(As + c * 2048 + tid * 8) = ab;
        }
        __syncthreads();

        bf16x8 af[4], bfr[4];
        #pragma unroll
        for (int i = 0; i < 4; ++i)
            af[i] = *(const bf16x8*)(As + (rbase + i * 16) * 32 + kfrag);
        #pragma unroll
        for (int j = 0; j < 4; ++j)
            bfr[j] = *(const bf16x8*)(Bs + (cbase + j * 16) * 32 + kfrag);

        #pragma unroll
        for (int i = 0; i < 4; ++i)
            #pragma unroll
            for (int j = 0; j < 4; ++j)
                acc[i][j] = __builtin_amdgcn_mfma_f32_16x16x32_bf16(
                    af[i], bfr[j], acc[i][j], 0, 0, 0);
        __syncthreads();
    }

    #pragma unroll
    for (int i = 0; i < 4; ++i) {
        int m0 = bm * 128 + wm * 64 + i * 16 + (l >> 4) * 4;
        #pragma unroll
        for (int j = 0; j < 4; ++j) {
            int n = bn * 128 + wn * 64 + j * 16 + (l & 15);
            float bb = b1[n] + b2[n];
            int hid = n & 127;          // g == bn
            #pragma unroll
            for (int r = 0; r < 4; ++r) {
                int m = m0 + r;
                int b = m >> tcs;
                int t = m & tcmask;
                int br = b >> 2, brow = b & 3;
                out[(((long)br * Tc + t) * 4 + bn) * 512 + brow * 128 + hid] =
                    acc[i][j][r] + bb;
            }
        }
    }
}

// ---------------------------------------------------------------------------
// Dual-role recurrence kernel. 256 blocks x 512 threads.
//   blocks 0-127  : layer-0 recurrence (producer)
//   blocks 128-255: layer-1 recurrence (consumer, K=256 stacked, depth-2 DMA)
// ---------------------------------------------------------------------------
#define BARRIER_()                                                             \
    do {                                                                       \
        asm volatile("s_waitcnt lgkmcnt(0)" ::: "memory");                     \
        __builtin_amdgcn_s_barrier();                                          \
        __builtin_amdgcn_sched_barrier(0);                                     \
    } while (0)

#define REC0_STEP(X, t)                                                        \
    {                                                                          \
        bf16x8 a[4];                                                           \
        _Pragma("unroll")                                                      \
        for (int ks = 0; ks < 4; ++ks) {                                       \
            int ba = (col * 256 + ks * 64 + lgroup * 16) ^ ((col & 7) << 4);   \
            a[ks] = *(const bf16x8*)((const char*)h_lds + ba);                 \
        }                                                                      \
        f32x4 acc[4];                                                          \
        _Pragma("unroll")                                                      \
        for (int g = 0; g < 4; ++g) acc[g] = (f32x4){0.f, 0.f, 0.f, 0.f};      \
        _Pragma("unroll")                                                      \
        for (int ks = 0; ks < 4; ++ks)                                         \
            _Pragma("unroll")                                                  \
            for (int g = 0; g < 4; ++g)                                        \
                acc[g] = __builtin_amdgcn_mfma_f32_16x16x32_bf16(              \
                    a[ks], __builtin_bit_cast(bf16x8, wreg[g][ks]), acc[g],    \
                    0, 0, 0);                                                  \
        if (lgroup == 0) {                                                     \
            _Pragma("unroll")                                                  \
            for (int r = 0; r < 4; ++r) {                                      \
                f32x4 v;                                                       \
                v[0] = acc[0][r]; v[1] = acc[1][r];                            \
                v[2] = acc[2][r]; v[3] = acc[3][r];                            \
                *(f32x4*)((char*)g_lds + r * 2048 + coff * 16) = v;            \
            }                                                                  \
        }                                                                      \
        BARRIER_();                                                            \
        {                                                                      \
            f32x4 gv = *(const f32x4*)((const char*)g_lds + tid * 16);         \
            float zi = gv[0] + X.x, zf = gv[1] + X.y;                          \
            float zg = gv[2] + X.z, zo = gv[3] + X.w;                          \
            c = sigm(zf) * c + sigm(zi) * tanhfast(zg);                        \
            h = sigm(zo) * tanhfast(c);                                        \
            *(bf16_t*)((char*)h_lds + hba) = (bf16_t)h;                        \
            h0qp[(long)(t) * 512] = (bf16_t)h;                                 \
        }                                                                      \
        if ((t) + 2 < Tc) {                                                    \
            long o = (long)((t) + 2) * 2048;                                   \
            X.x = xpt[o];        X.y = xpt[o + 512];                           \
            X.z = xpt[o + 1024]; X.w = xpt[o + 1536];                          \
        }                                                                      \
        if (((t) & (SUBS - 1)) == SUBS - 1)                                    \
            asm volatile("s_waitcnt vmcnt(0)" ::: "memory");                   \
        BARRIER_();                                                            \
        if ((((t) & (SUBS - 1)) == SUBS - 1) && tid == 0) {                    \
            __threadfence();                                                   \
            __hip_atomic_store(flagp + ((t) >> 4), 1u, __ATOMIC_RELEASE,       \
                               __HIP_MEMORY_SCOPE_AGENT);                      \
        }                                                                      \
    }

__global__ __launch_bounds__(512, 2) void lstm_dual(
    const float* __restrict__ xp4,   // [B/4][Tc][4][512] layer-0 projection
    const bf16_t* __restrict__ Wh0,  // Whh0 bf16 [512][128]
    const bf16_t* __restrict__ Wi1,  // Wih1 bf16 [512][128]
    const bf16_t* __restrict__ Wh1,  // Whh1 bf16 [512][128]
    const float* __restrict__ bih1, const float* __restrict__ bhh1,
    bf16_t* __restrict__ h0q,        // [128][Tc][512] swizzled h0 images
    unsigned* __restrict__ flags,    // [128][NCH]
    float* __restrict__ h0st, float* __restrict__ c0st,
    float* __restrict__ h1st, float* __restrict__ c1st,
    int Tc, int first, int subbase)
{
    __shared__ __align__(16) char pool[28 * 1024];
    int tid = threadIdx.x;
    int l = tid & 63;
    int wv = tid >> 6;                // wave 0..7
    int pair = blockIdx.x & 127;
    int r0 = pair * RB;
    int col = l & 15;
    int lgroup = l >> 4;              // 0..3
    int kreg = lgroup * 8;
    int coff = wv * 16 + col;         // owned gate-col (0..127)
    int erow = tid >> 7, ehid = tid & 127;
    const int hba = (erow * 256 + ehid * 2) ^ ((erow & 7) << 4);
    unsigned* flagp = flags + pair * NCH + subbase;

    if (blockIdx.x < 128) {
        // ================= producer: layer-0 recurrence =================
        bf16_t* h_lds = (bf16_t*)pool;           // 4 KB (16 rows, swizzled)
        float*  g_lds = (float*)(pool + 4096);   // 8 KB

        f32x4 wreg[4][4];
        #pragma unroll
        for (int g = 0; g < 4; ++g)
            #pragma unroll
            for (int ks = 0; ks < 4; ++ks)
                wreg[g][ks] = *(const f32x4*)(Wh0 + (long)(g * 128 + coff) * HID
                                              + ks * 32 + kreg);
        #pragma unroll
        for (int g = 0; g < 4; ++g)
            #pragma unroll
            for (int ks = 0; ks < 4; ++ks)
                asm volatile("" : "+a"(wreg[g][ks]));

        float c = first ? 0.f : c0st[(r0 + erow) * HID + ehid];
        float h = first ? 0.f : h0st[(r0 + erow) * HID + ehid];

        ((float2*)h_lds)[tid & 255] = make_float2(0.f, 0.f);   // zero 4 KB
        __syncthreads();
        *(bf16_t*)((char*)h_lds + hba) = (bf16_t)h;
        __syncthreads();

        const float* xpt = xp4 + (long)pair * Tc * 2048 + tid;
        bf16_t* h0qp = h0q + (long)pair * Tc * 512 + (hba >> 1);
        float4 xA, xB;
        xA.x = xpt[0];    xA.y = xpt[512];
        xA.z = xpt[1024]; xA.w = xpt[1536];
        if (Tc > 1) {
            xB.x = xpt[2048];        xB.y = xpt[2048 + 512];
            xB.z = xpt[2048 + 1024]; xB.w = xpt[2048 + 1536];
        } else {
            xB = make_float4(0.f, 0.f, 0.f, 0.f);
        }

        for (int tt = 0; tt < Tc; tt += 2) {
            REC0_STEP(xA, tt)
            REC0_STEP(xB, tt + 1)
        }

        h0st[(r0 + erow) * HID + ehid] = h;
        c0st[(r0 + erow) * HID + ehid] = c;
    } else {
        // == consumer: layer-1, K=256 stacked, depth-2 DMA, 2-barrier ew ==
        bf16_t* h0stg = (bf16_t*)pool;             // 4 slots x 4 KB
        bf16_t* h1_lds = (bf16_t*)(pool + 16384);  // 4 KB
        float*  g_lds = (float*)(pool + 20480);    // 8 KB (full gates)

        f32x4 wI[4][4], wH[4][4];
        #pragma unroll
        for (int g = 0; g < 4; ++g)
            #pragma unroll
            for (int ks = 0; ks < 4; ++ks) {
                long o = (long)(g * 128 + coff) * HID + ks * 32 + kreg;
                wI[g][ks] = *(const f32x4*)(Wi1 + o);
                wH[g][ks] = *(const f32x4*)(Wh1 + o);
            }
        #pragma unroll
        for (int g = 0; g < 4; ++g)
            #pragma unroll
            for (int ks = 0; ks < 4; ++ks) {
                asm volatile("" : "+a"(wI[g][ks]));
                asm volatile("" : "+a"(wH[g][ks]));
            }

        float4 bias1;
        bias1.x = bih1[ehid]       + bhh1[ehid];
        bias1.y = bih1[128 + ehid] + bhh1[128 + ehid];
        bias1.z = bih1[256 + ehid] + bhh1[256 + ehid];
        bias1.w = bih1[384 + ehid] + bhh1[384 + ehid];

        float c1 = first ? 0.f : c1st[(r0 + erow) * HID + ehid];
        float h1 = first ? 0.f : h1st[(r0 + erow) * HID + ehid];

        // zero h0stg (16 KB) + h1_lds (4 KB)
        #pragma unroll
        for (int i = 0; i < 5; ++i)
            ((float2*)pool)[i * 512 + tid] = make_float2(0.f, 0.f);
        __syncthreads();
        *(bf16_t*)((char*)h1_lds + hba) = (bf16_t)h1;
        __syncthreads();

        // prologue: wait chunk 0; stage images 0 and 1 into slots 0,1
        if (wv == 0) {
            while (__hip_atomic_load(flagp, __ATOMIC_ACQUIRE,
                                     __HIP_MEMORY_SCOPE_AGENT) == 0u)
                __builtin_amdgcn_s_sleep(2);
            __builtin_amdgcn_global_load_lds(
                (const __attribute__((address_space(1))) void*)(
                    h0q + (long)pair * Tc * 512 + l * 8),
                (__attribute__((address_space(3))) void*)h0stg, 16, 0, 0);
            if (Tc > 1)
                __builtin_amdgcn_global_load_lds(
                    (const __attribute__((address_space(1))) void*)(
                        h0q + ((long)pair * Tc + 1) * 512 + l * 8),
                    (__attribute__((address_space(3))) void*)(h0stg + 2048),
                    16, 0, 0);
            asm volatile("s_waitcnt vmcnt(0)" ::: "memory");
        }
        __syncthreads();

        for (int t = 0; t < Tc; ++t) {
            // issue DMA for image t+2 into slot (t+2)&3 (wave t&3)
            if (t + 2 < Tc && wv == (t & 3)) {
                if (((t + 2) & (SUBS - 1)) == 0) {
                    unsigned* fp = flagp + ((t + 2) >> 4);
                    while (__hip_atomic_load(fp, __ATOMIC_ACQUIRE,
                                             __HIP_MEMORY_SCOPE_AGENT) == 0u)
                        __builtin_amdgcn_s_sleep(2);
                }
                __builtin_amdgcn_global_load_lds(
                    (const __attribute__((address_space(1))) void*)(
                        h0q + ((long)pair * Tc + t + 2) * 512 + l * 8),
                    (__attribute__((address_space(3))) void*)(
                        h0stg + ((t + 2) & 3) * 2048), 16, 0, 0);
            }

            // phase A: full gates = Wi1@h0[t] + Wh1@h1[t-1] (K=256 stacked)
            const char* sb = (const char*)h0stg + (t & 3) * 4096;
            bf16x8 a0[4], a1[4];
            #pragma unroll
            for (int ks = 0; ks < 4; ++ks) {
                int ba = (col * 256 + ks * 64 + lgroup * 16) ^ ((col & 7) << 4);
                a0[ks] = *(const bf16x8*)(sb + ba);
                a1[ks] = *(const bf16x8*)((const char*)h1_lds + ba);
            }
            f32x4 acc[4];
            #pragma unroll
            for (int g = 0; g < 4; ++g) acc[g] = (f32x4){0.f, 0.f, 0.f, 0.f};
            #pragma unroll
            for (int ks = 0; ks < 4; ++ks)
                #pragma unroll
                for (int g = 0; g < 4; ++g)
                    acc[g] = __builtin_amdgcn_mfma_f32_16x16x32_bf16(
                        a0[ks], __builtin_bit_cast(bf16x8, wI[g][ks]), acc[g],
                        0, 0, 0);
            #pragma unroll
            for (int ks = 0; ks < 4; ++ks)
                #pragma unroll
                for (int g = 0; g < 4; ++g)
                    acc[g] = __builtin_amdgcn_mfma_f32_16x16x32_bf16(
                        a1[ks], __builtin_bit_cast(bf16x8, wH[g][ks]), acc[g],
                        0, 0, 0);
            if (lgroup == 0) {
                #pragma unroll
                for (int r = 0; r < 4; ++r) {
                    f32x4 v;
                    v[0] = acc[0][r]; v[1] = acc[1][r];
                    v[2] = acc[2][r]; v[3] = acc[3][r];
                    *(f32x4*)((char*)g_lds + r * 2048 + coff * 16) = v;
                }
            }
            BARRIER_();

            // phase B: ew (1 read + bias, 1 unit/thread)
            {
                f32x4 gv = *(const f32x4*)((const char*)g_lds + tid * 16);
                float zi = gv[0] + bias1.x;
                float zf = gv[1] + bias1.y;
                float zg = gv[2] + bias1.z;
                float zo = gv[3] + bias1.w;
                c1 = sigm(zf) * c1 + sigm(zi) * tanhfast(zg);
                h1 = sigm(zo) * tanhfast(c1);
                *(bf16_t*)((char*)h1_lds + hba) = (bf16_t)h1;
            }
            // wave ((t+3)&3) issued DMA(t+1) at step t-1: wait now
            if (t + 1 < Tc && wv == ((t + 3) & 3))
                asm volatile("s_waitcnt vmcnt(0)" ::: "memory");
            BARRIER_();
        }

        h1st[(r0 + erow) * HID + ehid] = h1;
        c1st[(r0 + erow) * HID + ehid] = c1;
    }
}

// ---------------------------------------------------------------------------
// FC head + softmax + state copy-out. One block per batch row, 128 threads.
// out layout: probs [512*10] | h_n [2*512*128] | c_n [2*512*128]
// ---------------------------------------------------------------------------
__global__ __launch_bounds__(128) void fc_head(
    const float* __restrict__ h0st, const float* __restrict__ c0st,
    const float* __restrict__ h1st, const float* __restrict__ c1st,
    const float* __restrict__ fc1w, const float* __restrict__ fc1b,
    const float* __restrict__ fc2w, const float* __restrict__ fc2b,
    float* __restrict__ out)
{
    __shared__ float h1_s[HID];
    __shared__ float hid_s[64];
    __shared__ float log_s[10];
    int t = threadIdx.x;
    int b = blockIdx.x;

    h1_s[t] = h1st[b * HID + t];
    __syncthreads();

    if (t < 64) {
        float a = fc1b[t];
        const float* wrow = fc1w + t * HID;
        #pragma unroll 4
        for (int k = 0; k < HID; ++k) a = fmaf(wrow[k], h1_s[k], a);
        hid_s[t] = fmaxf(a, 0.f);
    }
    __syncthreads();

    if (t < 10) {
        float a = fc2b[t];
        const float* wrow = fc2w + t * 64;
        #pragma unroll 4
        for (int k = 0; k < 64; ++k) a = fmaf(wrow[k], hid_s[k], a);
        log_s[t] = a;
    }
    __syncthreads();

    if (t == 0) {
        float m = log_s[0];
        #pragma unroll
        for (int j = 1; j < 10; ++j) m = fmaxf(m, log_s[j]);
        float e[10];
        float s = 0.f;
        #pragma unroll
        for (int j = 0; j < 10; ++j) { e[j] = __expf(log_s[j] - m); s += e[j]; }
        float inv = __builtin_amdgcn_rcpf(s);
        #pragma unroll
        for (int j = 0; j < 10; ++j) out[b * 10 + j] = e[j] * inv;
    }

    float* hn = out + BATCH * 10;
    float* cn = hn + 2 * BATCH * HID;
    hn[b * HID + t] = h0st[b * HID + t];
    hn[BATCH * HID + b * HID + t] = h1_s[t];
    cn[b * HID + t] = c0st[b * HID + t];
    cn[BATCH * HID + b * HID + t] = c1st[b * HID + t];
}

// ---------------------------------------------------------------------------
extern "C" void kernel_launch(void* const* d_in, const int* in_sizes, int n_in,
                              void* d_out, int out_size, void* d_ws, size_t ws_size,
                              hipStream_t stream) {
    const float* x    = (const float*)d_in[0];
    const float* Wih0 = (const float*)d_in[1];
    const float* Whh0 = (const float*)d_in[2];
    const float* bih0 = (const float*)d_in[3];
    const float* bhh0 = (const float*)d_in[4];
    const float* Wih1 = (const float*)d_in[5];
    const float* Whh1 = (const float*)d_in[6];
    const float* bih1 = (const float*)d_in[7];
    const float* bhh1 = (const float*)d_in[8];
    const float* fc1w = (const float*)d_in[9];
    const float* fc1b = (const float*)d_in[10];
    const float* fc2w = (const float*)d_in[11];
    const float* fc2b = (const float*)d_in[12];
    float* out = (float*)d_out;

    int Tc = SEQT;
    while (Tc > SUBS) {
        size_t need = (size_t)BATCH * Tc * GATES * 4        // xp4
                    + ((size_t)GATES * INPUTD + 3 * (size_t)GATES * HID) * 2
                    + (size_t)128 * Tc * 512 * 2            // h0q
                    + 4 * (size_t)BATCH * HID * 4
                    + 128 * NCH * 4 + 512;
        if (need <= ws_size) break;
        Tc >>= 1;
    }
    int tcs = __builtin_ctz((unsigned)Tc);

    float*    xp   = (float*)d_ws;
    bf16_t*   wb0  = (bf16_t*)(xp + (size_t)BATCH * Tc * GATES);
    bf16_t*   wb1  = wb0 + (size_t)GATES * INPUTD;
    bf16_t*   wh0b = wb1 + (size_t)GATES * HID;
    bf16_t*   wh1b = wh0b + (size_t)GATES * HID;
    bf16_t*   h0q  = wh1b + (size_t)GATES * HID;
    float*    h0st = (float*)(h0q + (size_t)128 * Tc * 512);
    float*    c0st = h0st + (size_t)BATCH * HID;
    float*    h1st = c0st + (size_t)BATCH * HID;
    float*    c1st = h1st + (size_t)BATCH * HID;
    unsigned* flags = (unsigned*)(c1st + (size_t)BATCH * HID);

    cvt_weights<<<449, 256, 0, stream>>>(Wih0, Wih1, Whh0, Whh1,
                                         wb0, wb1, wh0b, wh1b, flags);

    int nchunk = SEQT / Tc;
    dim3 gemm_grid(GATES / 128, (BATCH * Tc) / 128);

    for (int ci = 0; ci < nchunk; ++ci) {
        gemm_mfma<<<gemm_grid, 256, 0, stream>>>(
            x, wb0, bih0, bhh0, xp, INPUTD, tcs, Tc - 1, SEQT, ci * Tc);
        lstm_dual<<<256, 512, 0, stream>>>(
            xp, wh0b, wb1, wh1b, bih1, bhh1, h0q, flags,
            h0st, c0st, h1st, c1st, Tc, ci == 0, ci * (Tc / SUBS));
    }

    fc_head<<<BATCH, 128, 0, stream>>>(
        h0st, c0st, h1st, c1st, fc1w, fc1b, fc2w, fc2b, out);
}